// Round 1
// baseline (617.027 us; speedup 1.0000x reference)
//
#include <hip/hip_runtime.h>
#include <hip/hip_fp16.h>

// Performer (FAVOR+) attention, fp32, MI355X.
// B=2 H=8 N=8192 D=64 F=256. Rows flattened: R = 16*8192 = 131072.
//
// Pipeline (all on `stream`):
//   initK  : zero ws accumulators (stab/ctx/ksum) — required every call (replays).
//   stabK  : dd_k = K @ (nrm*P)^T, global max -> ws (monotone-uint atomicMax).
//   ctxK   : recompute dd_k, kp = ratio*(exp(dd-diag-stab)+eps),
//            ctx[f][e] += kp^T V, ksum[f] += kp   (fp32 atomics into ws).
//   qpK    : dd_q GEMM, per-row max, qp -> ws as fp16 (slab-sized).
//   outK   : out = (qp @ ctx) / (qp . ksum).

#define BH_  16
#define N_   8192
#define D_   64
#define F_   256
#define RTOT 131072

#define NRM   0.35355339059327379f   // 64^-0.25
#define RATIO 0.0625f                // 256^-0.5
#define DSC   0.0625f                // 0.5 * NRM^2
#define EPS_  1e-4f

// ws layout (float words)
#define CTX_W   16
#define KSUM_W  (CTX_W + BH_ * F_ * D_)   // 262160
#define ZERO_W  (KSUM_W + BH_ * F_)       // 266256
#define QP_OFF_BYTES ((size_t)ZERO_W * 4) // 1,065,024

__device__ __forceinline__ unsigned mapmax(float x) {
  unsigned u = __float_as_uint(x);
  return (u & 0x80000000u) ? ~u : (u | 0x80000000u);
}
__device__ __forceinline__ float unmapmax(unsigned u) {
  return __uint_as_float((u & 0x80000000u) ? (u & 0x7fffffffu) : ~u);
}

// ---- staging helpers (blockDim = 256) ----

// P (F x 64) -> Plt[d][f] transposed, scaled by NRM. Plt stride 256.
__device__ __forceinline__ void stage_Pt(const float* __restrict__ Pg, float* Plt, int tid) {
  int f = tid;  // 0..255
  #pragma unroll
  for (int d4 = 0; d4 < 16; ++d4) {
    float4 pv = *(const float4*)&Pg[f * 64 + d4 * 4];
    Plt[(d4 * 4 + 0) * 256 + f] = NRM * pv.x;
    Plt[(d4 * 4 + 1) * 256 + f] = NRM * pv.y;
    Plt[(d4 * 4 + 2) * 256 + f] = NRM * pv.z;
    Plt[(d4 * 4 + 3) * 256 + f] = NRM * pv.w;
  }
}

// 64 rows x 64 of X -> Xl[64][68] (raw values)
__device__ __forceinline__ void stage_rows(const float* __restrict__ Xg, long row0,
                                           float* Xl, int tid) {
  const float4* src = (const float4*)(Xg + row0 * 64);
  #pragma unroll
  for (int it = 0; it < 4; ++it) {
    int u = it * 256 + tid;        // float4 index 0..1023
    int r = u >> 4;
    int c4 = (u & 15) << 2;
    *(float4*)&Xl[r * 68 + c4] = src[u];
  }
}

// diag[r] = DSC * sum_d X[r][d]^2 for 64 rows
__device__ __forceinline__ void diag_64rows(const float* Xl, float* diagl, int tid) {
  int r = tid >> 2, qq = tid & 3;
  const float* row = &Xl[r * 68 + qq * 16];
  float4 x0 = *(const float4*)&row[0];
  float4 x1 = *(const float4*)&row[4];
  float4 x2 = *(const float4*)&row[8];
  float4 x3 = *(const float4*)&row[12];
  float p = 0.f;
  p = fmaf(x0.x, x0.x, p); p = fmaf(x0.y, x0.y, p); p = fmaf(x0.z, x0.z, p); p = fmaf(x0.w, x0.w, p);
  p = fmaf(x1.x, x1.x, p); p = fmaf(x1.y, x1.y, p); p = fmaf(x1.z, x1.z, p); p = fmaf(x1.w, x1.w, p);
  p = fmaf(x2.x, x2.x, p); p = fmaf(x2.y, x2.y, p); p = fmaf(x2.z, x2.z, p); p = fmaf(x2.w, x2.w, p);
  p = fmaf(x3.x, x3.x, p); p = fmaf(x3.y, x3.y, p); p = fmaf(x3.z, x3.z, p); p = fmaf(x3.w, x3.w, p);
  p += __shfl_xor(p, 1);
  p += __shfl_xor(p, 2);
  if (qq == 0) diagl[r] = DSC * p;
}

// 64x256 = Xl(64x64, stride 68) @ Plt(64x256)^T-ish. Thread (tr,tc): 4 rows x 16 f.
// f layout per thread: f = jj*64 + tc*4 + c   (jj 0..3, c 0..3), acc[i][jj*4+c].
__device__ __forceinline__ void gemm1_tile(const float* Xl, const float* Plt,
                                           int tr, int tc, float acc[4][16]) {
  #pragma unroll
  for (int d4 = 0; d4 < 64; d4 += 4) {
    float4 a0 = *(const float4*)&Xl[(tr * 4 + 0) * 68 + d4];
    float4 a1 = *(const float4*)&Xl[(tr * 4 + 1) * 68 + d4];
    float4 a2 = *(const float4*)&Xl[(tr * 4 + 2) * 68 + d4];
    float4 a3 = *(const float4*)&Xl[(tr * 4 + 3) * 68 + d4];
    float av[4][4] = {{a0.x, a0.y, a0.z, a0.w},
                      {a1.x, a1.y, a1.z, a1.w},
                      {a2.x, a2.y, a2.z, a2.w},
                      {a3.x, a3.y, a3.z, a3.w}};
    #pragma unroll
    for (int dj = 0; dj < 4; ++dj) {
      const float* prow = &Plt[(d4 + dj) * 256 + tc * 4];
      float4 b0 = *(const float4*)&prow[0];
      float4 b1 = *(const float4*)&prow[64];
      float4 b2 = *(const float4*)&prow[128];
      float4 b3 = *(const float4*)&prow[192];
      float bv[16] = {b0.x, b0.y, b0.z, b0.w, b1.x, b1.y, b1.z, b1.w,
                      b2.x, b2.y, b2.z, b2.w, b3.x, b3.y, b3.z, b3.w};
      #pragma unroll
      for (int i = 0; i < 4; ++i)
        #pragma unroll
        for (int j = 0; j < 16; ++j)
          acc[i][j] = fmaf(av[i][dj], bv[j], acc[i][j]);
    }
  }
}

// ---------------- kernels ----------------

__global__ void __launch_bounds__(256) initK(unsigned* ws) {
  for (int i = blockIdx.x * 256 + threadIdx.x; i < ZERO_W; i += gridDim.x * 256)
    ws[i] = 0u;
}

__global__ void __launch_bounds__(256) stabK(const float* __restrict__ Kg,
                                             const float* __restrict__ Pg,
                                             unsigned* __restrict__ stab_ws) {
  extern __shared__ float sm[];
  float* Plt = sm;               // 16384
  float* Xl  = sm + 16384;       // 64*68 = 4352
  float* red = sm + 16384 + 4352;// 8
  int tid = threadIdx.x;
  stage_Pt(Pg, Plt, tid);
  long row0 = (long)blockIdx.x * 64;
  stage_rows(Kg, row0, Xl, tid);
  __syncthreads();
  int tr = tid >> 4, tc = tid & 15;
  float acc[4][16] = {};
  gemm1_tile(Xl, Plt, tr, tc, acc);
  float m = -3.4e38f;
  #pragma unroll
  for (int i = 0; i < 4; ++i)
    #pragma unroll
    for (int j = 0; j < 16; ++j) m = fmaxf(m, acc[i][j]);
  #pragma unroll
  for (int off = 1; off < 64; off <<= 1) m = fmaxf(m, __shfl_xor(m, off));
  if ((tid & 63) == 0) red[tid >> 6] = m;
  __syncthreads();
  if (tid == 0) {
    m = fmaxf(fmaxf(red[0], red[1]), fmaxf(red[2], red[3]));
    atomicMax(stab_ws, mapmax(m));
  }
}

__global__ void __launch_bounds__(256) ctxK(const float* __restrict__ Kg,
                                            const float* __restrict__ Vg,
                                            const float* __restrict__ Pg,
                                            const unsigned* __restrict__ stab_ws,
                                            float* __restrict__ ctx_g,
                                            float* __restrict__ ksum_g) {
  extern __shared__ float sm[];
  float* Plt   = sm;                       // 16384
  float* kpl   = sm + 16384;               // 64*260 = 16640
  float* Xl    = sm + 16384 + 16640;       // 4352
  float* diagl = sm + 16384 + 16640 + 4352;// 64
  int tid = threadIdx.x;
  int bh = blockIdx.x >> 4, ch = blockIdx.x & 15;
  long rowbase = (long)bh * N_ + (long)ch * 512;
  stage_Pt(Pg, Plt, tid);
  float stab = unmapmax(*stab_ws);
  int tr = tid >> 4, tc = tid & 15;
  int lane = tid & 63, w = tid >> 6;
  int fl = lane >> 3, el = lane & 7;
  int fbase = w * 64 + fl * 8, ebase = el * 8;
  float acc2[8][8] = {};
  float ksacc[16] = {};
  for (int t = 0; t < 8; ++t) {
    __syncthreads();                        // prev GEMM2 done with Xl/kpl (also covers Plt)
    stage_rows(Kg, rowbase + t * 64, Xl, tid);
    __syncthreads();
    diag_64rows(Xl, diagl, tid);
    __syncthreads();
    float acc1[4][16] = {};
    gemm1_tile(Xl, Plt, tr, tc, acc1);
    #pragma unroll
    for (int i = 0; i < 4; ++i) {
      float dmi = diagl[tr * 4 + i];
      #pragma unroll
      for (int jj = 0; jj < 4; ++jj) {
        float4 kv;
        kv.x = RATIO * (__expf(acc1[i][jj * 4 + 0] - dmi - stab) + EPS_);
        kv.y = RATIO * (__expf(acc1[i][jj * 4 + 1] - dmi - stab) + EPS_);
        kv.z = RATIO * (__expf(acc1[i][jj * 4 + 2] - dmi - stab) + EPS_);
        kv.w = RATIO * (__expf(acc1[i][jj * 4 + 3] - dmi - stab) + EPS_);
        ksacc[jj * 4 + 0] += kv.x; ksacc[jj * 4 + 1] += kv.y;
        ksacc[jj * 4 + 2] += kv.z; ksacc[jj * 4 + 3] += kv.w;
        *(float4*)&kpl[(tr * 4 + i) * 260 + jj * 64 + tc * 4] = kv;
      }
    }
    __syncthreads();                        // GEMM1 reads of Xl done; kpl written
    stage_rows(Vg, rowbase + t * 64, Xl, tid);
    __syncthreads();
    #pragma unroll 2
    for (int r = 0; r < 64; ++r) {
      float4 a0 = *(const float4*)&kpl[r * 260 + fbase];
      float4 a1 = *(const float4*)&kpl[r * 260 + fbase + 4];
      float4 b0 = *(const float4*)&Xl[r * 68 + ebase];
      float4 b1 = *(const float4*)&Xl[r * 68 + ebase + 4];
      float av[8] = {a0.x, a0.y, a0.z, a0.w, a1.x, a1.y, a1.z, a1.w};
      float bv[8] = {b0.x, b0.y, b0.z, b0.w, b1.x, b1.y, b1.z, b1.w};
      #pragma unroll
      for (int ff = 0; ff < 8; ++ff)
        #pragma unroll
        for (int ee = 0; ee < 8; ++ee)
          acc2[ff][ee] = fmaf(av[ff], bv[ee], acc2[ff][ee]);
    }
  }
  float* cg = ctx_g + (long)bh * F_ * D_;
  #pragma unroll
  for (int ff = 0; ff < 8; ++ff)
    #pragma unroll
    for (int ee = 0; ee < 8; ++ee)
      atomicAdd(&cg[(fbase + ff) * 64 + ebase + ee], acc2[ff][ee]);
  #pragma unroll
  for (int j = 0; j < 16; ++j) {
    ksacc[j] += __shfl_xor(ksacc[j], 16);
    ksacc[j] += __shfl_xor(ksacc[j], 32);
  }
  if (lane < 16) {
    float* kg = ksum_g + bh * F_;
    #pragma unroll
    for (int jj = 0; jj < 4; ++jj)
      #pragma unroll
      for (int c = 0; c < 4; ++c)
        atomicAdd(&kg[jj * 64 + lane * 4 + c], ksacc[jj * 4 + c]);
  }
}

__global__ void __launch_bounds__(256) qpK(const float* __restrict__ Qg,
                                           const float* __restrict__ Pg,
                                           __half* __restrict__ qp_ws, long slab_base) {
  extern __shared__ float sm[];
  float* Plt   = sm;                 // 16384
  float* Xl    = sm + 16384;         // 4352
  float* diagl = sm + 16384 + 4352;  // 64
  int tid = threadIdx.x;
  long row0 = slab_base + (long)blockIdx.x * 64;
  stage_Pt(Pg, Plt, tid);
  stage_rows(Qg, row0, Xl, tid);
  __syncthreads();
  diag_64rows(Xl, diagl, tid);
  __syncthreads();
  int tr = tid >> 4, tc = tid & 15;
  float acc[4][16] = {};
  gemm1_tile(Xl, Plt, tr, tc, acc);
  float rm[4];
  #pragma unroll
  for (int i = 0; i < 4; ++i) {
    float m = acc[i][0];
    #pragma unroll
    for (int j = 1; j < 16; ++j) m = fmaxf(m, acc[i][j]);
    m = fmaxf(m, __shfl_xor(m, 1));
    m = fmaxf(m, __shfl_xor(m, 2));
    m = fmaxf(m, __shfl_xor(m, 4));
    m = fmaxf(m, __shfl_xor(m, 8));
    rm[i] = m;
  }
  __half* dst = qp_ws + (row0 - slab_base) * 256;
  #pragma unroll
  for (int i = 0; i < 4; ++i) {
    float dmi = diagl[tr * 4 + i];
    #pragma unroll
    for (int jj = 0; jj < 4; ++jj) {
      float v0 = RATIO * (__expf(acc[i][jj * 4 + 0] - dmi - rm[i]) + EPS_);
      float v1 = RATIO * (__expf(acc[i][jj * 4 + 1] - dmi - rm[i]) + EPS_);
      float v2 = RATIO * (__expf(acc[i][jj * 4 + 2] - dmi - rm[i]) + EPS_);
      float v3 = RATIO * (__expf(acc[i][jj * 4 + 3] - dmi - rm[i]) + EPS_);
      __half2 h01 = __floats2half2_rn(v0, v1);
      __half2 h23 = __floats2half2_rn(v2, v3);
      uint2 pk;
      pk.x = *(unsigned*)&h01;
      pk.y = *(unsigned*)&h23;
      *(uint2*)&dst[(long)(tr * 4 + i) * 256 + jj * 64 + tc * 4] = pk;
    }
  }
}

__global__ void __launch_bounds__(256) outK(const __half* __restrict__ qp_ws,
                                            const float* __restrict__ ctx_g,
                                            const float* __restrict__ ksum_g,
                                            float* __restrict__ outg, long slab_base) {
  extern __shared__ float sm[];
  float* qpl  = sm;                  // 256*68 = 17408
  float* ctxl = sm + 17408;          // 16384
  float* ksl  = sm + 17408 + 16384;  // 256
  int tid = threadIdx.x;
  long row0 = slab_base + (long)blockIdx.x * 256;
  int bh = (int)(row0 / N_);
  for (int u = tid; u < F_ * D_; u += 256) ctxl[u] = ctx_g[(long)bh * F_ * D_ + u];
  ksl[tid] = ksum_g[bh * F_ + tid];
  int rg = tid >> 3, eg = tid & 7;
  int swz = (rg & 7) << 2;
  float acc[8][8] = {};
  float ds[8] = {};
  const __half* qsrc = qp_ws + (row0 - slab_base) * 256;
  #pragma unroll 1
  for (int jj = 0; jj < 4; ++jj) {
    __syncthreads();                 // prev chunk reads done (also covers ctxl/ksl staging)
    #pragma unroll
    for (int it = 0; it < 16; ++it) {
      int u = it * 256 + tid;        // 0..4095, 4 halfs each
      int r = u >> 4;
      int c4 = (u & 15) << 2;
      uint2 raw = *(const uint2*)&qsrc[(long)r * 256 + jj * 64 + c4];
      __half2 h01 = *(__half2*)&raw.x;
      __half2 h23 = *(__half2*)&raw.y;
      float2 f01 = __half22float2(h01);
      float2 f23 = __half22float2(h23);
      float4 vv = make_float4(f01.x, f01.y, f23.x, f23.y);
      *(float4*)&qpl[r * 68 + (c4 ^ (((r >> 3) & 7) << 2))] = vv;
    }
    __syncthreads();
    #pragma unroll
    for (int f4 = 0; f4 < 16; ++f4) {
      float4 a[8];
      #pragma unroll
      for (int ii = 0; ii < 8; ++ii)
        a[ii] = *(const float4*)&qpl[(rg * 8 + ii) * 68 + ((f4 * 4) ^ swz)];
      float4 ks4 = *(const float4*)&ksl[jj * 64 + f4 * 4];
      float4 b0[4], b1[4];
      #pragma unroll
      for (int cc = 0; cc < 4; ++cc) {
        b0[cc] = *(const float4*)&ctxl[(jj * 64 + f4 * 4 + cc) * 64 + eg * 8];
        b1[cc] = *(const float4*)&ctxl[(jj * 64 + f4 * 4 + cc) * 64 + eg * 8 + 4];
      }
      #pragma unroll
      for (int ii = 0; ii < 8; ++ii) {
        float ax[4] = {a[ii].x, a[ii].y, a[ii].z, a[ii].w};
        ds[ii] = fmaf(ax[0], ks4.x, ds[ii]);
        ds[ii] = fmaf(ax[1], ks4.y, ds[ii]);
        ds[ii] = fmaf(ax[2], ks4.z, ds[ii]);
        ds[ii] = fmaf(ax[3], ks4.w, ds[ii]);
        #pragma unroll
        for (int cc = 0; cc < 4; ++cc) {
          acc[ii][0] = fmaf(ax[cc], b0[cc].x, acc[ii][0]);
          acc[ii][1] = fmaf(ax[cc], b0[cc].y, acc[ii][1]);
          acc[ii][2] = fmaf(ax[cc], b0[cc].z, acc[ii][2]);
          acc[ii][3] = fmaf(ax[cc], b0[cc].w, acc[ii][3]);
          acc[ii][4] = fmaf(ax[cc], b1[cc].x, acc[ii][4]);
          acc[ii][5] = fmaf(ax[cc], b1[cc].y, acc[ii][5]);
          acc[ii][6] = fmaf(ax[cc], b1[cc].z, acc[ii][6]);
          acc[ii][7] = fmaf(ax[cc], b1[cc].w, acc[ii][7]);
        }
      }
    }
  }
  float* og = outg + row0 * 64;
  #pragma unroll
  for (int ii = 0; ii < 8; ++ii) {
    float dinv = 1.0f / ds[ii];
    float4 o0 = make_float4(acc[ii][0] * dinv, acc[ii][1] * dinv,
                            acc[ii][2] * dinv, acc[ii][3] * dinv);
    float4 o1 = make_float4(acc[ii][4] * dinv, acc[ii][5] * dinv,
                            acc[ii][6] * dinv, acc[ii][7] * dinv);
    *(float4*)&og[(rg * 8 + ii) * 64 + eg * 8] = o0;
    *(float4*)&og[(rg * 8 + ii) * 64 + eg * 8 + 4] = o1;
  }
}

// ---------------- host ----------------

extern "C" void kernel_launch(void* const* d_in, const int* in_sizes, int n_in,
                              void* d_out, int out_size, void* d_ws, size_t ws_size,
                              hipStream_t stream) {
  (void)in_sizes; (void)n_in; (void)out_size;
  const float* q = (const float*)d_in[0];
  const float* k = (const float*)d_in[1];
  const float* v = (const float*)d_in[2];
  const float* P = (const float*)d_in[3];
  float* out = (float*)d_out;

  unsigned* stab = (unsigned*)d_ws;
  float* ctx  = (float*)d_ws + CTX_W;
  float* ksum = (float*)d_ws + KSUM_W;
  __half* qpws = (__half*)((char*)d_ws + QP_OFF_BYTES);

  const size_t smem_stab = (16384 + 4352 + 8) * 4;            // 82,976
  const size_t smem_ctx  = (16384 + 16640 + 4352 + 64) * 4;   // 149,760
  const size_t smem_qp   = (16384 + 4352 + 64) * 4;           // 83,200
  const size_t smem_out  = (17408 + 16384 + 256) * 4;         // 136,192

  hipLaunchKernelGGL(initK, dim3(256), dim3(256), 0, stream, (unsigned*)d_ws);
  hipLaunchKernelGGL(stabK, dim3(RTOT / 64), dim3(256), smem_stab, stream, k, P, stab);
  hipLaunchKernelGGL(ctxK, dim3(BH_ * 16), dim3(256), smem_ctx, stream, k, v, P, stab, ctx, ksum);

  // slab qp through ws (fp16, 512 B per row)
  size_t avail = ws_size > QP_OFF_BYTES ? ws_size - QP_OFF_BYTES : 0;
  long slab = (long)(avail / 512) / 256 * 256;
  if (slab > RTOT) slab = RTOT;
  if (slab < 256) slab = 256;  // assume ws is at least ~1.2 MB
  for (long base = 0; base < RTOT; base += slab) {
    long rows = (RTOT - base < slab) ? (RTOT - base) : slab;
    hipLaunchKernelGGL(qpK, dim3((unsigned)(rows / 64)), dim3(256), smem_qp, stream,
                       q, P, qpws, base);
    hipLaunchKernelGGL(outK, dim3((unsigned)(rows / 256)), dim3(256), smem_out, stream,
                       qpws, ctx, ksum, out, base);
  }
}

// Round 2
// 172.082 us; speedup vs baseline: 3.5856x; 3.5856x over previous
//
#include <hip/hip_runtime.h>

// Performer (FAVOR+) attention, MI355X, split-bf16 MFMA (hi/lo 3-pass).
// B=2 H=8 N=8192 D=64 F=256; rows R = 131072.
// initK -> stabK (global max, single-bf16 MFMA)
//       -> ctxK (dd_k split-MFMA, exp, ctx=kp^T V split-MFMA, fp32 atomics)
//       -> qoK  (dd_q split-MFMA, rowmax+den, out=qp@ctx split-MFMA, fused)

typedef __bf16 bf16;
typedef __bf16 bf16x8 __attribute__((ext_vector_type(8)));
typedef float f32x4 __attribute__((ext_vector_type(4)));

#define N_    8192
#define BH_   16
#define NRM   0.35355339059327379f   // 64^-0.25
#define RATIO 0.0625f                // 256^-0.5
#define DSC   0.0625f                // 0.5*NRM^2
#define REPS  6.25e-6f               // RATIO*1e-4

#define CTX_W  16
#define KSUM_W (CTX_W + BH_*256*64)     // 262160
#define ZERO_W (KSUM_W + BH_*256)       // 266256

static __device__ __forceinline__ unsigned mapmax(float x){
  unsigned u=__float_as_uint(x); return (u&0x80000000u)? ~u : (u|0x80000000u);
}
static __device__ __forceinline__ float unmapmax(unsigned u){
  return __uint_as_float((u&0x80000000u)? (u&0x7fffffffu) : ~u);
}
static __device__ __forceinline__ f32x4 mfma16(bf16x8 a, bf16x8 b, f32x4 c){
  return __builtin_amdgcn_mfma_f32_16x16x32_bf16(a,b,c,0,0,0);
}
static __device__ __forceinline__ void ld8(const float* __restrict__ p, float* x){
  float4 a=*(const float4*)p; float4 b=*(const float4*)(p+4);
  x[0]=a.x; x[1]=a.y; x[2]=a.z; x[3]=a.w; x[4]=b.x; x[5]=b.y; x[6]=b.z; x[7]=b.w;
}
static __device__ __forceinline__ void split8(const float* x, bf16x8& h, bf16x8& l){
  #pragma unroll
  for(int i=0;i<8;++i){ bf16 hi=(bf16)x[i]; h[i]=hi; l[i]=(bf16)(x[i]-(float)hi); }
}
static __device__ __forceinline__ void cvt8(const float* x, bf16x8& h){
  #pragma unroll
  for(int i=0;i<8;++i) h[i]=(bf16)x[i];
}
// P-hat (NRM*P) b-fragments for a wave's 64-wide f strip: [ft 0..3][ks 0..1]
static __device__ __forceinline__ void load_P_frags(const float* __restrict__ Pg,
    int fb, int l15, int g, bf16x8 (&ph)[4][2], bf16x8 (&pl)[4][2]){
  #pragma unroll
  for(int ft=0;ft<4;++ft)
    #pragma unroll
    for(int ks=0;ks<2;++ks){
      float x[8]; ld8(&Pg[(fb+16*ft+l15)*64+32*ks+8*g],x);
      #pragma unroll
      for(int i=0;i<8;++i) x[i]*=NRM;
      split8(x,ph[ft][ks],pl[ft][ks]);
    }
}

// ---------------- kernels ----------------

__global__ void __launch_bounds__(256) initK(unsigned* ws){
  for(int i=blockIdx.x*256+threadIdx.x;i<ZERO_W;i+=gridDim.x*256) ws[i]=0u;
}

// global max of dd_k (single-bf16; error ~0.016 on stab -> ~1e-5 on out)
__global__ void __launch_bounds__(256) stabK(const float* __restrict__ Kg,
                                             const float* __restrict__ Pg,
                                             unsigned* __restrict__ stab_ws){
  __shared__ float red[4];
  int tid=threadIdx.x, w=tid>>6, lane=tid&63, l15=lane&15, g=lane>>4;
  int fb=w*64;
  long row0=(long)blockIdx.x*64;
  bf16x8 pb[4][2];
  #pragma unroll
  for(int ft=0;ft<4;++ft)
    #pragma unroll
    for(int ks=0;ks<2;++ks){
      float x[8]; ld8(&Pg[(fb+16*ft+l15)*64+32*ks+8*g],x);
      #pragma unroll
      for(int i=0;i<8;++i) x[i]*=NRM;
      cvt8(x,pb[ft][ks]);
    }
  bf16x8 ka[4][2];
  #pragma unroll
  for(int rt=0;rt<4;++rt)
    #pragma unroll
    for(int ks=0;ks<2;++ks){
      float x[8]; ld8(&Kg[(row0+16*rt+l15)*64+32*ks+8*g],x);
      cvt8(x,ka[rt][ks]);
    }
  f32x4 zero={0.f,0.f,0.f,0.f};
  f32x4 acc[4][4];
  #pragma unroll
  for(int rt=0;rt<4;++rt)
    #pragma unroll
    for(int ft=0;ft<4;++ft) acc[rt][ft]=zero;
  #pragma unroll
  for(int rt=0;rt<4;++rt)
    #pragma unroll
    for(int ft=0;ft<4;++ft)
      #pragma unroll
      for(int ks=0;ks<2;++ks)
        acc[rt][ft]=mfma16(ka[rt][ks],pb[ft][ks],acc[rt][ft]);
  float m=-3.4e38f;
  #pragma unroll
  for(int rt=0;rt<4;++rt)
    #pragma unroll
    for(int ft=0;ft<4;++ft)
      #pragma unroll
      for(int r=0;r<4;++r) m=fmaxf(m,acc[rt][ft][r]);
  #pragma unroll
  for(int off=1;off<64;off<<=1) m=fmaxf(m,__shfl_xor(m,off));
  if(lane==0) red[w]=m;
  __syncthreads();
  if(tid==0){
    m=fmaxf(fmaxf(red[0],red[1]),fmaxf(red[2],red[3]));
    atomicMax(stab_ws,mapmax(m));
  }
}

// kp + ctx/ksum accumulation. grid = 16 bh * 32 chunks; chunk = 256 rows.
// No __syncthreads needed: kpt LDS regions are wave-local; K/V go global->regs.
__global__ void __launch_bounds__(256,2) ctxK(const float* __restrict__ Kg,
    const float* __restrict__ Vg, const float* __restrict__ Pg,
    const unsigned* __restrict__ stab_ws, float* __restrict__ ctx_g,
    float* __restrict__ ksum_g){
  __shared__ __align__(16) bf16 kpt_h[256*40];
  __shared__ __align__(16) bf16 kpt_l[256*40];
  int tid=threadIdx.x, w=tid>>6, lane=tid&63, l15=lane&15, g=lane>>4;
  int fb=w*64;
  int bh=blockIdx.x>>5, ch=blockIdx.x&31;
  long rowbase=(long)bh*N_ + ch*256;
  float stab=unmapmax(*stab_ws);
  bf16x8 pb_h[4][2], pb_l[4][2];
  load_P_frags(Pg,fb,l15,g,pb_h,pb_l);
  f32x4 zero={0.f,0.f,0.f,0.f};
  f32x4 cacc[4][4];
  #pragma unroll
  for(int mt=0;mt<4;++mt)
    #pragma unroll
    for(int et=0;et<4;++et) cacc[mt][et]=zero;
  float ksacc[4]={0.f,0.f,0.f,0.f};
  #pragma unroll 1
  for(int it=0;it<8;++it){
    long n0=rowbase+it*32;
    // K a-frags (split) + row sums of squares
    bf16x8 ka_h[2][2], ka_l[2][2];
    float dsq[2];
    #pragma unroll
    for(int rt=0;rt<2;++rt){
      float ss=0.f;
      #pragma unroll
      for(int ks=0;ks<2;++ks){
        float x[8]; ld8(&Kg[(n0+16*rt+l15)*64+32*ks+8*g],x);
        #pragma unroll
        for(int i=0;i<8;++i) ss=fmaf(x[i],x[i],ss);
        split8(x,ka_h[rt][ks],ka_l[rt][ks]);
      }
      ss+=__shfl_xor(ss,16); ss+=__shfl_xor(ss,32);
      dsq[rt]=DSC*ss;
    }
    // dd = K-hat @ P-hat^T (3-pass split)
    f32x4 dacc[2][4];
    #pragma unroll
    for(int rt=0;rt<2;++rt)
      #pragma unroll
      for(int ft=0;ft<4;++ft) dacc[rt][ft]=zero;
    #pragma unroll
    for(int rt=0;rt<2;++rt)
      #pragma unroll
      for(int ft=0;ft<4;++ft)
        #pragma unroll
        for(int ks=0;ks<2;++ks){
          dacc[rt][ft]=mfma16(ka_h[rt][ks],pb_h[ft][ks],dacc[rt][ft]);
          dacc[rt][ft]=mfma16(ka_h[rt][ks],pb_l[ft][ks],dacc[rt][ft]);
          dacc[rt][ft]=mfma16(ka_l[rt][ks],pb_h[ft][ks],dacc[rt][ft]);
        }
    float dg[2][4];
    #pragma unroll
    for(int rt=0;rt<2;++rt)
      #pragma unroll
      for(int r=0;r<4;++r) dg[rt][r]=__shfl(dsq[rt],4*g+r);
    // kp = RATIO*exp(dd - diag - stab) + REPS; write transposed [f][n] hi/lo
    #pragma unroll
    for(int rt=0;rt<2;++rt)
      #pragma unroll
      for(int ft=0;ft<4;++ft){
        int f=fb+16*ft+l15;
        #pragma unroll
        for(int r=0;r<4;++r){
          float kp=fmaf(RATIO,__expf(dacc[rt][ft][r]-dg[rt][r]-stab),REPS);
          ksacc[ft]+=kp;
          bf16 hb=(bf16)kp; bf16 lb=(bf16)(kp-(float)hb);
          int nn=16*rt+4*g+r;
          kpt_h[f*40+nn]=hb; kpt_l[f*40+nn]=lb;
        }
      }
    // V b-frags (split) straight from global
    bf16x8 vb_h[4], vb_l[4];
    #pragma unroll
    for(int et=0;et<4;++et){
      float x[8];
      #pragma unroll
      for(int j=0;j<8;++j) x[j]=Vg[(n0+8*g+j)*64+16*et+l15];
      split8(x,vb_h[et],vb_l[et]);
    }
    // ctx += kp^T @ V (3-pass split); kpt is wave-local (same-wave RAW only)
    #pragma unroll
    for(int mt=0;mt<4;++mt){
      bf16x8 a_h=*(const bf16x8*)&kpt_h[(fb+16*mt+l15)*40+8*g];
      bf16x8 a_l=*(const bf16x8*)&kpt_l[(fb+16*mt+l15)*40+8*g];
      #pragma unroll
      for(int et=0;et<4;++et){
        cacc[mt][et]=mfma16(a_h,vb_h[et],cacc[mt][et]);
        cacc[mt][et]=mfma16(a_h,vb_l[et],cacc[mt][et]);
        cacc[mt][et]=mfma16(a_l,vb_h[et],cacc[mt][et]);
      }
    }
  }
  float* cg=ctx_g+(long)bh*16384;
  #pragma unroll
  for(int mt=0;mt<4;++mt)
    #pragma unroll
    for(int et=0;et<4;++et)
      #pragma unroll
      for(int r=0;r<4;++r)
        atomicAdd(&cg[(fb+16*mt+4*g+r)*64+16*et+l15],cacc[mt][et][r]);
  #pragma unroll
  for(int ft=0;ft<4;++ft){
    float s=ksacc[ft];
    s+=__shfl_xor(s,16); s+=__shfl_xor(s,32);
    if(g==0) atomicAdd(&ksum_g[bh*256+fb+16*ft+l15],s);
  }
}

// fused qp + out. grid = 16 bh * 32 chunks; chunk = 256 rows; 2 barriers/iter.
__global__ void __launch_bounds__(256,2) qoK(const float* __restrict__ Qg,
    const float* __restrict__ Pg, const float* __restrict__ ctx_g,
    const float* __restrict__ ksum_g, float* __restrict__ outg){
  __shared__ float qpt_h[32*132];   // packed bf16 pairs (hi plane), [n][f/2]
  __shared__ float qpt_l[32*132];   // lo plane
  __shared__ float rmaxl[4][32];
  __shared__ float denl[4][32];
  int tid=threadIdx.x, w=tid>>6, lane=tid&63, l15=lane&15, g=lane>>4;
  int fb=w*64;
  int bh=blockIdx.x>>5, ch=blockIdx.x&31;
  long rowbase=(long)bh*N_ + ch*256;
  bf16x8 pb_h[4][2], pb_l[4][2];
  load_P_frags(Pg,fb,l15,g,pb_h,pb_l);
  float ksv[4];
  #pragma unroll
  for(int ft=0;ft<4;++ft) ksv[ft]=ksum_g[bh*256+fb+16*ft+l15];
  // ctx b-frags for this wave's e-tile (et = w), split
  bf16x8 cb_h[8], cb_l[8];
  #pragma unroll
  for(int ks=0;ks<8;++ks){
    float x[8];
    #pragma unroll
    for(int j=0;j<8;++j) x[j]=ctx_g[(long)bh*16384+(32*ks+8*g+j)*64+16*w+l15];
    split8(x,cb_h[ks],cb_l[ks]);
  }
  f32x4 zero={0.f,0.f,0.f,0.f};
  #pragma unroll 1
  for(int it=0;it<8;++it){
    long n0=rowbase+it*32;
    // Q a-frags (split) + diag
    bf16x8 qa_h[2][2], qa_l[2][2];
    float dsq[2];
    #pragma unroll
    for(int rt=0;rt<2;++rt){
      float ss=0.f;
      #pragma unroll
      for(int ks=0;ks<2;++ks){
        float x[8]; ld8(&Qg[(n0+16*rt+l15)*64+32*ks+8*g],x);
        #pragma unroll
        for(int i=0;i<8;++i) ss=fmaf(x[i],x[i],ss);
        split8(x,qa_h[rt][ks],qa_l[rt][ks]);
      }
      ss+=__shfl_xor(ss,16); ss+=__shfl_xor(ss,32);
      dsq[rt]=DSC*ss;
    }
    f32x4 dacc[2][4];
    #pragma unroll
    for(int rt=0;rt<2;++rt)
      #pragma unroll
      for(int ft=0;ft<4;++ft) dacc[rt][ft]=zero;
    #pragma unroll
    for(int rt=0;rt<2;++rt)
      #pragma unroll
      for(int ft=0;ft<4;++ft)
        #pragma unroll
        for(int ks=0;ks<2;++ks){
          dacc[rt][ft]=mfma16(qa_h[rt][ks],pb_h[ft][ks],dacc[rt][ft]);
          dacc[rt][ft]=mfma16(qa_h[rt][ks],pb_l[ft][ks],dacc[rt][ft]);
          dacc[rt][ft]=mfma16(qa_l[rt][ks],pb_h[ft][ks],dacc[rt][ft]);
        }
    float dg[2][4];
    #pragma unroll
    for(int rt=0;rt<2;++rt)
      #pragma unroll
      for(int r=0;r<4;++r) dg[rt][r]=__shfl(dsq[rt],4*g+r);
    // per-wave rowmax over its f-strip
    #pragma unroll
    for(int rt=0;rt<2;++rt)
      #pragma unroll
      for(int r=0;r<4;++r){
        float m=fmaxf(fmaxf(dacc[rt][0][r],dacc[rt][1][r]),
                      fmaxf(dacc[rt][2][r],dacc[rt][3][r]));
        m=fmaxf(m,__shfl_xor(m,1)); m=fmaxf(m,__shfl_xor(m,2));
        m=fmaxf(m,__shfl_xor(m,4)); m=fmaxf(m,__shfl_xor(m,8));
        if(l15==0) rmaxl[w][16*rt+4*g+r]=m;
      }
    __syncthreads();   // rowmax planes ready
    // qp, den partials, packed qpt writes
    #pragma unroll
    for(int rt=0;rt<2;++rt)
      #pragma unroll
      for(int r=0;r<4;++r){
        int nn=16*rt+4*g+r;
        float rm=fmaxf(fmaxf(rmaxl[0][nn],rmaxl[1][nn]),
                       fmaxf(rmaxl[2][nn],rmaxl[3][nn]));
        float dp=0.f;
        #pragma unroll
        for(int ft=0;ft<4;++ft){
          float qp=fmaf(RATIO,__expf(dacc[rt][ft][r]-dg[rt][r]-rm),REPS);
          dp=fmaf(qp,ksv[ft],dp);
          bf16 hb=(bf16)qp; bf16 lb=(bf16)(qp-(float)hb);
          unsigned mine=(unsigned)__builtin_bit_cast(unsigned short,hb)
                       |((unsigned)__builtin_bit_cast(unsigned short,lb)<<16);
          unsigned other=(unsigned)__shfl_xor((int)mine,1);
          int f=fb+16*ft+l15;
          unsigned wv=(lane&1)? ((other>>16)|(mine&0xffff0000u))
                              : ((mine&0xffffu)|(other<<16));
          float* bp=(lane&1)? qpt_l : qpt_h;
          bp[nn*132+(f>>1)]=__uint_as_float(wv);
        }
        dp+=__shfl_xor(dp,1); dp+=__shfl_xor(dp,2);
        dp+=__shfl_xor(dp,4); dp+=__shfl_xor(dp,8);
        if(l15==0) denl[w][nn]=dp;
      }
    __syncthreads();   // qpt + denl ready
    // out = qp @ ctx (3-pass split), this wave's e-tile
    f32x4 oacc[2]; oacc[0]=zero; oacc[1]=zero;
    #pragma unroll
    for(int ks=0;ks<8;++ks)
      #pragma unroll
      for(int mt=0;mt<2;++mt){
        bf16x8 a_h=*(const bf16x8*)&qpt_h[(16*mt+l15)*132+16*ks+4*g];
        bf16x8 a_l=*(const bf16x8*)&qpt_l[(16*mt+l15)*132+16*ks+4*g];
        oacc[mt]=mfma16(a_h,cb_h[ks],oacc[mt]);
        oacc[mt]=mfma16(a_h,cb_l[ks],oacc[mt]);
        oacc[mt]=mfma16(a_l,cb_h[ks],oacc[mt]);
      }
    #pragma unroll
    for(int mt=0;mt<2;++mt)
      #pragma unroll
      for(int r=0;r<4;++r){
        int nn=16*mt+4*g+r;
        float den=denl[0][nn]+denl[1][nn]+denl[2][nn]+denl[3][nn];
        outg[(n0+nn)*64+16*w+l15]=oacc[mt][r]/den;
      }
  }
}

// ---------------- host ----------------

extern "C" void kernel_launch(void* const* d_in, const int* in_sizes, int n_in,
                              void* d_out, int out_size, void* d_ws, size_t ws_size,
                              hipStream_t stream) {
  (void)in_sizes; (void)n_in; (void)out_size; (void)ws_size;
  const float* q = (const float*)d_in[0];
  const float* k = (const float*)d_in[1];
  const float* v = (const float*)d_in[2];
  const float* P = (const float*)d_in[3];
  float* out = (float*)d_out;

  unsigned* stab = (unsigned*)d_ws;
  float* ctx  = (float*)d_ws + CTX_W;
  float* ksum = (float*)d_ws + KSUM_W;

  hipLaunchKernelGGL(initK, dim3(256), dim3(256), 0, stream, (unsigned*)d_ws);
  hipLaunchKernelGGL(stabK, dim3(2048), dim3(256), 0, stream, k, P, stab);
  hipLaunchKernelGGL(ctxK, dim3(512), dim3(256), 0, stream, k, v, P, stab, ctx, ksum);
  hipLaunchKernelGGL(qoK, dim3(512), dim3(256), 0, stream, q, P, ctx, ksum, out);
}